// Round 1
// baseline (241.192 us; speedup 1.0000x reference)
//
#include <hip/hip_runtime.h>

#define BOND   64
#define SITES  256
#define HALF   128
#define NBATCH 128
#define OUTD   10

typedef const float __attribute__((address_space(1)))* gas1_fp;
typedef float __attribute__((address_space(3)))* gas3_fp;

__device__ __forceinline__ void gload_lds16(const float* g, float* l) {
  // each lane copies 16B from its own g to ldsbase + lane*16
  __builtin_amdgcn_global_load_lds((gas1_fp)g, (gas3_fp)l, 16, 0, 0);
}

// One 64-thread block per (batch, side) chain. Lane = output bond index.
// Left  (side 0): v <- v^T * M_s, s = 0..127          (v starts at lvec)
// Right (side 1): w <- M_s * w,   s = 255..128        (w starts at rvec)
// M_s = I + x0*c0[s] + x1*c1[s];  cores layout [s][l][r][feat] (feat innermost)
__global__ void __launch_bounds__(64)
mps_chain_kernel(const float* __restrict__ input,   // [128][256][2]
                 const float* __restrict__ cores,   // [256][64][64][2]
                 const float* __restrict__ lvec,    // [64]
                 const float* __restrict__ rvec,    // [64]
                 float* __restrict__ ws) {          // [2][128][64]
  __shared__ __align__(16) float buf[2][BOND * BOND * 2];  // 2 x 32KB double buffer
  __shared__ __align__(16) float xsh[HALF * 2];            // this chain's x values
  __shared__ float vsh[BOND];                              // propagated vector

  const int lane = (int)threadIdx.x;
  const int bid  = (int)blockIdx.x;
  const int side = bid >> 7;           // 0 = left, 1 = right
  const int b    = bid & (NBATCH - 1);

  // stage the 256 x-values for this (b, side): 64 lanes x float4
  ((float4*)xsh)[lane] =
      ((const float4*)(input + (size_t)b * SITES * 2 + side * HALF * 2))[lane];

  float vcur = side ? rvec[lane] : lvec[lane];
  vsh[lane] = vcur;

  // prologue: prefetch first site into buf[0]
  {
    const float* g0 = cores + (size_t)(side ? (SITES - 1) : 0) * (BOND * BOND * 2);
    #pragma unroll
    for (int c = 0; c < 32; ++c)
      gload_lds16(g0 + c * 256 + lane * 4, &buf[0][c * 256]);
  }

  for (int i = 0; i < HALF; ++i) {
    const float* B = buf[i & 1];
    // prefetch next site into the alternate buffer (addresses are data-independent)
    {
      const int inext = (i < HALF - 1) ? (i + 1) : i;   // last iter: harmless re-fetch
      const int snext = side ? (SITES - 1 - inext) : inext;
      const float* gn = cores + (size_t)snext * (BOND * BOND * 2);
      float* ldsn = buf[(i & 1) ^ 1];
      #pragma unroll
      for (int c = 0; c < 32; ++c)
        gload_lds16(gn + c * 256 + lane * 4, ldsn + c * 256);
    }
    // wait for current site's 32 loads; the 32 just issued may stay in flight
    asm volatile("s_waitcnt vmcnt(32)" ::: "memory");

    float acc0 = 0.f, acc1 = 0.f;
    if (side == 0) {
      // v_new[r=lane] = v[lane] + x0*sum_l v[l]*c0[l][lane] + x1*sum_l v[l]*c1[l][lane]
      #pragma unroll
      for (int l = 0; l < BOND; ++l) {
        float2 c2 = ((const float2*)B)[(l << 6) + lane];  // c0,c1 at [l][lane]
        float vl = vsh[l];                                // broadcast read
        acc0 = __builtin_fmaf(vl, c2.x, acc0);
        acc1 = __builtin_fmaf(vl, c2.y, acc1);
      }
    } else {
      // w_new[l=lane] = w[lane] + x0*sum_r c0[lane][r]*w[r] + x1*sum_r c1[lane][r]*w[r]
      // rotation r=(lane+j)&63 keeps LDS reads conflict-free
      #pragma unroll
      for (int j = 0; j < BOND; ++j) {
        const int r = (lane + j) & 63;
        float2 c2 = ((const float2*)B)[(lane << 6) + r];  // c0,c1 at [lane][r]
        float wr = vsh[r];
        acc0 = __builtin_fmaf(wr, c2.x, acc0);
        acc1 = __builtin_fmaf(wr, c2.y, acc1);
      }
    }
    const int xi = side ? (HALF - 1 - i) : i;
    const float2 xx = ((const float2*)xsh)[xi];
    const float vnew = __builtin_fmaf(xx.x, acc0, __builtin_fmaf(xx.y, acc1, vcur));
    // single wave: DS pipe is per-wave in-order, all reads above already issued
    vsh[lane] = vnew;
    vcur = vnew;
  }

  ws[(size_t)side * (NBATCH * BOND) + b * BOND + lane] = vcur;
}

// logits[b][o] = sum_{m,r} vL[b][m] * oc[o][m][r] * vR[b][r]
__global__ void __launch_bounds__(64)
mps_combine_kernel(const float* __restrict__ oc,   // [10][64][64]
                   const float* __restrict__ ws,   // [2][128][64]
                   float* __restrict__ out) {      // [128][10]
  __shared__ float vl[BOND];
  const int lane = (int)threadIdx.x;
  const int b = (int)blockIdx.x;
  vl[lane] = ws[b * BOND + lane];
  const float myvr = ws[NBATCH * BOND + b * BOND + lane];
  // single wave: LDS write-then-read is in-order, no barrier needed
  float res[OUTD];
  #pragma unroll
  for (int o = 0; o < OUTD; ++o) {
    float acc = 0.f;
    #pragma unroll
    for (int m = 0; m < BOND; ++m)
      acc = __builtin_fmaf(vl[m], oc[((o * BOND) + m) * BOND + lane], acc);
    acc *= myvr;
    #pragma unroll
    for (int off = 32; off > 0; off >>= 1)
      acc += __shfl_xor(acc, off, 64);
    res[o] = acc;
  }
  if (lane == 0) {
    #pragma unroll
    for (int o = 0; o < OUTD; ++o) out[b * OUTD + o] = res[o];
  }
}

extern "C" void kernel_launch(void* const* d_in, const int* in_sizes, int n_in,
                              void* d_out, int out_size, void* d_ws, size_t ws_size,
                              hipStream_t stream) {
  const float* input = (const float*)d_in[0];   // [128][256][2]
  const float* cores = (const float*)d_in[1];   // [256][64][64][2]
  const float* oc    = (const float*)d_in[2];   // [10][64][64]
  const float* lvec  = (const float*)d_in[3];   // [64]
  const float* rvec  = (const float*)d_in[4];   // [64]
  float* ws  = (float*)d_ws;                    // 2*128*64 floats = 64KB
  float* out = (float*)d_out;                   // [128][10]

  hipLaunchKernelGGL(mps_chain_kernel, dim3(2 * NBATCH), dim3(64), 0, stream,
                     input, cores, lvec, rvec, ws);
  hipLaunchKernelGGL(mps_combine_kernel, dim3(NBATCH), dim3(64), 0, stream,
                     oc, ws, out);
}

// Round 2
// 213.533 us; speedup vs baseline: 1.1295x; 1.1295x over previous
//
#include <hip/hip_runtime.h>

#define BOND   64
#define SITES  256
#define HALF   128
#define NBATCH 128
#define OUTD   10

// d_ws float layout:
//   P0 : [0 .. 1048576)        left-packed  [128 steps][32 g][64 j] float4
//   P1 : [1048576 .. 2097152)  right-packed (transposed, step k = site 255-k)
//   vecs: [2097152 .. 2113536) [2][128][64] propagated end vectors
#define P1_OFF   1048576
#define VEC_OFF  2097152
#define SITE_F4  2048          // float4s per packed site (64*64*2 floats)

// ---------------------------------------------------------------------------
// Pack kernel: one block per site. Rewrites cores[s][l][r][f] into per-side
// layouts so the chain kernel's lane (=output bond index) loads 16B coalesced:
//   side0 step s=i:      P0[i][g][j] = {c0[2g][j], c1[2g][j], c0[2g+1][j], c1[2g+1][j]}
//   side1 step k=255-s:  P1[k][g][j] = {c0[j][2g], c1[j][2g], c0[j][2g+1], c1[j][2g+1]}
// ---------------------------------------------------------------------------
__global__ void __launch_bounds__(256)
mps_pack_kernel(const float* __restrict__ cores, float* __restrict__ P) {
  const int s = (int)blockIdx.x;          // 0..255
  const int t = (int)threadIdx.x;
  const int j = t & 63;
  const int g0 = (t >> 6) * 8;            // 4 groups of 8 g-values
  const bool right = s >= HALF;
  const int step = right ? (SITES - 1 - s) : s;
  float4* out = (float4*)(P + (right ? P1_OFF : 0)) + (size_t)step * SITE_F4;
  const float* c = cores + (size_t)s * (BOND * BOND * 2);
  if (!right) {
    #pragma unroll
    for (int k = 0; k < 8; ++k) {
      const int g = g0 + k;
      float2 a = ((const float2*)(c + (2 * g) * (BOND * 2)))[j];
      float2 b = ((const float2*)(c + (2 * g + 1) * (BOND * 2)))[j];
      out[g * 64 + j] = make_float4(a.x, a.y, b.x, b.y);
    }
  } else {
    #pragma unroll
    for (int k = 0; k < 8; ++k) {
      const int g = g0 + k;
      // cores[s][j][2g..2g+1][0..1] is 16B contiguous
      float4 v = *(const float4*)(c + j * (BOND * 2) + 4 * g);
      out[g * 64 + j] = v;
    }
  }
}

// ---------------------------------------------------------------------------
// Chain kernel: 128 blocks x 64 threads. Block = (side, batch-pair).
// One wave propagates TWO batches' vectors through 128 sites, streaming the
// shared per-site matrix straight into registers (double-buffered float4[32]).
//   side0: v_new[r] = v[r] + x0*sum_l v[l]*c0[l][r] + x1*sum_l v[l]*c1[l][r]
//   side1 (via packed transpose): same code shape with l<->r swapped.
// ---------------------------------------------------------------------------
__global__ void __launch_bounds__(64, 1)
mps_chain_kernel(const float* __restrict__ input,   // [128][256][2]
                 const float* __restrict__ P,       // packed cores (in ws)
                 const float* __restrict__ lvec,
                 const float* __restrict__ rvec,
                 float* __restrict__ vout) {        // ws + VEC_OFF
  __shared__ float vsh0[BOND];
  __shared__ float vsh1[BOND];
  __shared__ __align__(16) float xsh[2][HALF * 2];

  const int lane = (int)threadIdx.x;
  const int bid  = (int)blockIdx.x;
  const int side = bid >> 6;               // 0: batches use sites 0..127, 1: 255..128
  const int bp   = bid & 63;               // batch pair index
  const int b0   = 2 * bp;
  const int b1   = 2 * bp + 1;

  // stage x values for both chains (128 sites x 2 feats = 64 float4 each)
  ((float4*)xsh[0])[lane] =
      ((const float4*)(input + (size_t)b0 * SITES * 2 + side * HALF * 2))[lane];
  ((float4*)xsh[1])[lane] =
      ((const float4*)(input + (size_t)b1 * SITES * 2 + side * HALF * 2))[lane];

  const float e = side ? rvec[lane] : lvec[lane];
  float vc0 = e, vc1 = e;
  vsh0[lane] = e;
  vsh1[lane] = e;

  const float4* base = (const float4*)(P + (side ? P1_OFF : 0));

  float4 A[32], Bv[32];
  // prologue: site-step 0
  #pragma unroll
  for (int g = 0; g < 32; ++g) A[g] = base[(size_t)0 * SITE_F4 + g * 64 + lane];

  #define CHAIN_COMPUTE(BUF, I)                                              \
  {                                                                          \
    float a00 = 0.f, a01 = 0.f, a10 = 0.f, a11 = 0.f;                        \
    _Pragma("unroll")                                                        \
    for (int g2 = 0; g2 < 16; ++g2) {                                        \
      const float4 w0 = ((const float4*)vsh0)[g2];                           \
      const float4 w1 = ((const float4*)vsh1)[g2];                           \
      const float4 m0 = BUF[2 * g2];                                         \
      const float4 m1 = BUF[2 * g2 + 1];                                     \
      a00 = __builtin_fmaf(w0.x, m0.x, a00);                                 \
      a01 = __builtin_fmaf(w0.x, m0.y, a01);                                 \
      a10 = __builtin_fmaf(w1.x, m0.x, a10);                                 \
      a11 = __builtin_fmaf(w1.x, m0.y, a11);                                 \
      a00 = __builtin_fmaf(w0.y, m0.z, a00);                                 \
      a01 = __builtin_fmaf(w0.y, m0.w, a01);                                 \
      a10 = __builtin_fmaf(w1.y, m0.z, a10);                                 \
      a11 = __builtin_fmaf(w1.y, m0.w, a11);                                 \
      a00 = __builtin_fmaf(w0.z, m1.x, a00);                                 \
      a01 = __builtin_fmaf(w0.z, m1.y, a01);                                 \
      a10 = __builtin_fmaf(w1.z, m1.x, a10);                                 \
      a11 = __builtin_fmaf(w1.z, m1.y, a11);                                 \
      a00 = __builtin_fmaf(w0.w, m1.z, a00);                                 \
      a01 = __builtin_fmaf(w0.w, m1.w, a01);                                 \
      a10 = __builtin_fmaf(w1.w, m1.z, a10);                                 \
      a11 = __builtin_fmaf(w1.w, m1.w, a11);                                 \
    }                                                                        \
    const int xi = side ? (HALF - 1 - (I)) : (I);                            \
    const float2 x0 = ((const float2*)xsh[0])[xi];                           \
    const float2 x1 = ((const float2*)xsh[1])[xi];                           \
    vc0 = __builtin_fmaf(x0.x, a00, __builtin_fmaf(x0.y, a01, vc0));         \
    vc1 = __builtin_fmaf(x1.x, a10, __builtin_fmaf(x1.y, a11, vc1));         \
    vsh0[lane] = vc0;                                                        \
    vsh1[lane] = vc1;                                                        \
  }

  for (int i = 0; i < HALF; i += 2) {
    // prefetch step i+1 while computing step i
    #pragma unroll
    for (int g = 0; g < 32; ++g)
      Bv[g] = base[(size_t)(i + 1) * SITE_F4 + g * 64 + lane];
    CHAIN_COMPUTE(A, i);
    // prefetch step i+2 (clamped; last refetch harmless) while computing i+1
    const int inx = (i + 2 < HALF) ? (i + 2) : (HALF - 1);
    #pragma unroll
    for (int g = 0; g < 32; ++g)
      A[g] = base[(size_t)inx * SITE_F4 + g * 64 + lane];
    CHAIN_COMPUTE(Bv, i + 1);
  }

  vout[(size_t)side * (NBATCH * BOND) + b0 * BOND + lane] = vc0;
  vout[(size_t)side * (NBATCH * BOND) + b1 * BOND + lane] = vc1;
}

// ---------------------------------------------------------------------------
// logits[b][o] = sum_{m,r} vL[b][m] * oc[o][m][r] * vR[b][r]
// ---------------------------------------------------------------------------
__global__ void __launch_bounds__(64)
mps_combine_kernel(const float* __restrict__ oc,    // [10][64][64]
                   const float* __restrict__ vecs,  // ws + VEC_OFF
                   float* __restrict__ out) {       // [128][10]
  __shared__ float vl[BOND];
  const int lane = (int)threadIdx.x;
  const int b = (int)blockIdx.x;
  vl[lane] = vecs[b * BOND + lane];
  const float myvr = vecs[NBATCH * BOND + b * BOND + lane];
  float res[OUTD];
  #pragma unroll
  for (int o = 0; o < OUTD; ++o) {
    float acc = 0.f;
    #pragma unroll
    for (int m = 0; m < BOND; ++m)
      acc = __builtin_fmaf(vl[m], oc[((o * BOND) + m) * BOND + lane], acc);
    acc *= myvr;
    #pragma unroll
    for (int off = 32; off > 0; off >>= 1)
      acc += __shfl_xor(acc, off, 64);
    res[o] = acc;
  }
  if (lane == 0) {
    #pragma unroll
    for (int o = 0; o < OUTD; ++o) out[b * OUTD + o] = res[o];
  }
}

extern "C" void kernel_launch(void* const* d_in, const int* in_sizes, int n_in,
                              void* d_out, int out_size, void* d_ws, size_t ws_size,
                              hipStream_t stream) {
  const float* input = (const float*)d_in[0];   // [128][256][2]
  const float* cores = (const float*)d_in[1];   // [256][64][64][2]
  const float* oc    = (const float*)d_in[2];   // [10][64][64]
  const float* lvec  = (const float*)d_in[3];   // [64]
  const float* rvec  = (const float*)d_in[4];   // [64]
  float* ws  = (float*)d_ws;
  float* out = (float*)d_out;                   // [128][10]

  hipLaunchKernelGGL(mps_pack_kernel, dim3(SITES), dim3(256), 0, stream,
                     cores, ws);
  hipLaunchKernelGGL(mps_chain_kernel, dim3(2 * NBATCH / 2), dim3(64), 0, stream,
                     input, ws, lvec, rvec, ws + VEC_OFF);
  hipLaunchKernelGGL(mps_combine_kernel, dim3(NBATCH), dim3(64), 0, stream,
                     oc, ws + VEC_OFF, out);
}

// Round 3
// 135.699 us; speedup vs baseline: 1.7774x; 1.5736x over previous
//
#include <hip/hip_runtime.h>

#define BOND   64
#define SITES  256
#define HALF   128
#define NBATCH 128
#define OUTD   10

// d_ws float layout:
//   P0 : [0 .. 1048576)        left-packed  [128 steps][32 g][64 j] float4
//   P1 : [1048576 .. 2097152)  right-packed (transposed, step k = site 255-k)
//   vecs: [2097152 .. 2113536) [2][128][64] propagated end vectors
#define P1_OFF   1048576
#define VEC_OFF  2097152
#define SITE_F4  2048          // float4s per packed site (64*64*2 floats)
#define LPITCH   132           // LDS transpose pitch (floats), 16B-aligned rows

// ---------------------------------------------------------------------------
// Pack kernel: one block per site, LDS transpose so BOTH global reads and
// writes are fully coalesced.
//   side0 step s:        P0[s][g][j]     = {c0[2g][j], c1[2g][j], c0[2g+1][j], c1[2g+1][j]}
//   side1 step 255-s:    P1[255-s][g][j] = {c0[j][2g], c1[j][2g], c0[j][2g+1], c1[j][2g+1]}
// cores[s] is [l=64][r=64][f=2] = 8192 floats; LDS row l = 128 floats, pitch 132.
// ---------------------------------------------------------------------------
__global__ void __launch_bounds__(256)
mps_pack_kernel(const float* __restrict__ cores, float* __restrict__ P) {
  __shared__ __align__(16) float ld[64 * LPITCH];
  const int s = (int)blockIdx.x;
  const int t = (int)threadIdx.x;
  const float4* src = (const float4*)(cores + (size_t)s * 8192);
  #pragma unroll
  for (int k = 0; k < 8; ++k) {
    const int m = t + 256 * k;              // float4 index in [0,2048)
    const int row = m >> 5;                 // l
    const int c4  = m & 31;                 // float4 within row
    *(float4*)&ld[row * LPITCH + c4 * 4] = src[m];
  }
  __syncthreads();
  const bool right = s >= HALF;
  const int step = right ? (SITES - 1 - s) : s;
  float4* out = (float4*)(P + (right ? P1_OFF : 0)) + (size_t)step * SITE_F4;
  #pragma unroll
  for (int k = 0; k < 8; ++k) {
    const int m = t + 256 * k;              // out float4 index = g*64 + j
    const int g = m >> 6;
    const int j = m & 63;
    float4 v;
    if (!right) {
      const float2 a  = *(const float2*)&ld[(2 * g) * LPITCH + 2 * j];
      const float2 b2 = *(const float2*)&ld[(2 * g + 1) * LPITCH + 2 * j];
      v = make_float4(a.x, a.y, b2.x, b2.y);
    } else {
      v = *(const float4*)&ld[j * LPITCH + 4 * g];
    }
    out[m] = v;
  }
}

// ---------------------------------------------------------------------------
// Chain kernel: 128 blocks x 256 threads (4 waves). Block = (side, batch pair).
// Split-K: wave w owns l (side0) / r (side1) range [16w, 16w+16).
// Per step: 8x float4 register-streamed matrix chunk (double-buffered),
// 64 FMAs, LDS partial + 1 barrier + all-reduce, x-combine, private v-window.
// ---------------------------------------------------------------------------
__global__ void __launch_bounds__(256, 1)
mps_chain_kernel(const float* __restrict__ input,   // [128][256][2]
                 const float* __restrict__ P,       // packed cores (in ws)
                 const float* __restrict__ lvec,
                 const float* __restrict__ rvec,
                 float* __restrict__ vout) {        // ws + VEC_OFF
  __shared__ __align__(16) float pa[2][4][BOND][4];   // [stepparity][wave][lane][4]
  __shared__ __align__(16) float vshw[4][2][BOND];    // wave-private v copies
  __shared__ __align__(16) float xsh[2][HALF * 2];

  const int t    = (int)threadIdx.x;
  const int w    = t >> 6;
  const int lane = t & 63;
  const int side = (int)blockIdx.x & 1;    // pins each side to its own XCD set
  const int pair = (int)blockIdx.x >> 1;
  const int b0   = 2 * pair;
  const int b1   = 2 * pair + 1;

  if (w == 0)
    ((float4*)xsh[0])[lane] =
        ((const float4*)(input + (size_t)b0 * SITES * 2 + side * HALF * 2))[lane];
  else if (w == 1)
    ((float4*)xsh[1])[lane] =
        ((const float4*)(input + (size_t)b1 * SITES * 2 + side * HALF * 2))[lane];
  // first barrier (step 0's) orders xsh before any use

  const float e = side ? rvec[lane] : lvec[lane];
  float vc0 = e, vc1 = e;
  vshw[w][0][lane] = e;
  vshw[w][1][lane] = e;
  float4 v0[4], v1[4];
  #pragma unroll
  for (int qq = 0; qq < 4; ++qq) {          // wave-private, DS in-order: safe
    v0[qq] = ((const float4*)vshw[w][0])[4 * w + qq];
    v1[qq] = ((const float4*)vshw[w][1])[4 * w + qq];
  }

  // wave w's chunk: g = 8w+j, element [step*2048 + g*64 + lane]
  const float4* base = (const float4*)(P + (side ? P1_OFF : 0)) +
                       (size_t)(8 * w) * 64 + lane;

  float4 A[8], B[8];
  #pragma unroll
  for (int j = 0; j < 8; ++j) A[j] = base[j * 64];   // step 0

  #define STEP(CUR, NXT, I)                                                  \
  {                                                                          \
    const int inx = ((I) + 1 < HALF) ? (I) + 1 : (I);                        \
    _Pragma("unroll")                                                        \
    for (int j = 0; j < 8; ++j) NXT[j] = base[(size_t)inx * 2048 + j * 64];  \
    float a00 = 0.f, a01 = 0.f, a10 = 0.f, a11 = 0.f;                        \
    _Pragma("unroll")                                                        \
    for (int qq = 0; qq < 4; ++qq) {                                         \
      const float4 m0 = CUR[2 * qq], m1 = CUR[2 * qq + 1];                   \
      const float4 u0 = v0[qq], u1 = v1[qq];                                 \
      a00 = __builtin_fmaf(u0.x, m0.x, a00);                                 \
      a01 = __builtin_fmaf(u0.x, m0.y, a01);                                 \
      a10 = __builtin_fmaf(u1.x, m0.x, a10);                                 \
      a11 = __builtin_fmaf(u1.x, m0.y, a11);                                 \
      a00 = __builtin_fmaf(u0.y, m0.z, a00);                                 \
      a01 = __builtin_fmaf(u0.y, m0.w, a01);                                 \
      a10 = __builtin_fmaf(u1.y, m0.z, a10);                                 \
      a11 = __builtin_fmaf(u1.y, m0.w, a11);                                 \
      a00 = __builtin_fmaf(u0.z, m1.x, a00);                                 \
      a01 = __builtin_fmaf(u0.z, m1.y, a01);                                 \
      a10 = __builtin_fmaf(u1.z, m1.x, a10);                                 \
      a11 = __builtin_fmaf(u1.z, m1.y, a11);                                 \
      a00 = __builtin_fmaf(u0.w, m1.z, a00);                                 \
      a01 = __builtin_fmaf(u0.w, m1.w, a01);                                 \
      a10 = __builtin_fmaf(u1.w, m1.z, a10);                                 \
      a11 = __builtin_fmaf(u1.w, m1.w, a11);                                 \
    }                                                                        \
    *(float4*)pa[(I) & 1][w][lane] = make_float4(a00, a01, a10, a11);        \
    __syncthreads();                                                         \
    const float4 s0 = *(const float4*)pa[(I) & 1][0][lane];                  \
    const float4 s1 = *(const float4*)pa[(I) & 1][1][lane];                  \
    const float4 s2 = *(const float4*)pa[(I) & 1][2][lane];                  \
    const float4 s3 = *(const float4*)pa[(I) & 1][3][lane];                  \
    const float r00 = (s0.x + s1.x) + (s2.x + s3.x);                         \
    const float r01 = (s0.y + s1.y) + (s2.y + s3.y);                         \
    const float r10 = (s0.z + s1.z) + (s2.z + s3.z);                         \
    const float r11 = (s0.w + s1.w) + (s2.w + s3.w);                         \
    const int xi = side ? (HALF - 1 - (I)) : (I);                            \
    const float2 x0 = ((const float2*)xsh[0])[xi];                           \
    const float2 x1 = ((const float2*)xsh[1])[xi];                           \
    vc0 = __builtin_fmaf(x0.x, r00, __builtin_fmaf(x0.y, r01, vc0));         \
    vc1 = __builtin_fmaf(x1.x, r10, __builtin_fmaf(x1.y, r11, vc1));         \
    vshw[w][0][lane] = vc0;                                                  \
    vshw[w][1][lane] = vc1;                                                  \
    _Pragma("unroll")                                                        \
    for (int qq = 0; qq < 4; ++qq) {                                         \
      v0[qq] = ((const float4*)vshw[w][0])[4 * w + qq];                      \
      v1[qq] = ((const float4*)vshw[w][1])[4 * w + qq];                      \
    }                                                                        \
  }

  for (int i = 0; i < HALF; i += 2) {
    STEP(A, B, i);
    STEP(B, A, i + 1);
  }
  #undef STEP

  if (w == 0) {
    vout[((size_t)side * NBATCH + b0) * BOND + lane] = vc0;
    vout[((size_t)side * NBATCH + b1) * BOND + lane] = vc1;
  }
}

// ---------------------------------------------------------------------------
// logits[b][o] = sum_{m,r} vL[b][m] * oc[o][m][r] * vR[b][r]
// ---------------------------------------------------------------------------
__global__ void __launch_bounds__(64)
mps_combine_kernel(const float* __restrict__ oc,    // [10][64][64]
                   const float* __restrict__ vecs,  // ws + VEC_OFF
                   float* __restrict__ out) {       // [128][10]
  __shared__ float vl[BOND];
  const int lane = (int)threadIdx.x;
  const int b = (int)blockIdx.x;
  vl[lane] = vecs[b * BOND + lane];
  const float myvr = vecs[NBATCH * BOND + b * BOND + lane];
  float res[OUTD];
  #pragma unroll
  for (int o = 0; o < OUTD; ++o) {
    float acc = 0.f;
    #pragma unroll
    for (int m = 0; m < BOND; ++m)
      acc = __builtin_fmaf(vl[m], oc[((o * BOND) + m) * BOND + lane], acc);
    acc *= myvr;
    #pragma unroll
    for (int off = 32; off > 0; off >>= 1)
      acc += __shfl_xor(acc, off, 64);
    res[o] = acc;
  }
  if (lane == 0) {
    #pragma unroll
    for (int o = 0; o < OUTD; ++o) out[b * OUTD + o] = res[o];
  }
}

extern "C" void kernel_launch(void* const* d_in, const int* in_sizes, int n_in,
                              void* d_out, int out_size, void* d_ws, size_t ws_size,
                              hipStream_t stream) {
  const float* input = (const float*)d_in[0];   // [128][256][2]
  const float* cores = (const float*)d_in[1];   // [256][64][64][2]
  const float* oc    = (const float*)d_in[2];   // [10][64][64]
  const float* lvec  = (const float*)d_in[3];   // [64]
  const float* rvec  = (const float*)d_in[4];   // [64]
  float* ws  = (float*)d_ws;
  float* out = (float*)d_out;                   // [128][10]

  hipLaunchKernelGGL(mps_pack_kernel, dim3(SITES), dim3(256), 0, stream,
                     cores, ws);
  hipLaunchKernelGGL(mps_chain_kernel, dim3(NBATCH), dim3(256), 0, stream,
                     input, ws, lvec, rvec, ws + VEC_OFF);
  hipLaunchKernelGGL(mps_combine_kernel, dim3(NBATCH), dim3(64), 0, stream,
                     oc, ws + VEC_OFF, out);
}